// Round 1
// baseline (22339.880 us; speedup 1.0000x reference)
//
// R0: correctness-first multi-kernel implementation.
// - Precompute input GEMM (time-independent) + source = ctx@Wa_c.T once.
// - bf16 MFMA (16x16x32) for all GEMMs, fp32 accumulate, fp32 elementwise.
// - Per step: gates GEMM -> LSTM cell -> target GEMM -> energy -> softmax
//   -> context -> h_tilde GEMM.  ~1800 dispatches total in the graph.
#include <hip/hip_runtime.h>
#include <stdint.h>

#define BB 64
#define TT 256
#define SS 256
#define HH 1024
#define II 1024
#define H4 4096
#define H2 2048

static const size_t BTH = (size_t)BB * TT * HH;   // 16777216
static const size_t BTS = (size_t)BB * TT * SS;   // 4194304

typedef unsigned short u16;
typedef __attribute__((ext_vector_type(8))) short short8;
typedef __attribute__((ext_vector_type(4))) float f32x4;

__device__ inline u16 f2bf(float x) {
    union { float f; uint32_t u; } v; v.f = x;
    uint32_t r = (v.u + 0x7FFFu + ((v.u >> 16) & 1u)) >> 16;
    return (u16)r;
}
__device__ inline float bf2f(u16 b) {
    union { float f; uint32_t u; } v; v.u = ((uint32_t)b) << 16;
    return v.f;
}
__device__ inline float fexp2(float x) {
#if __has_builtin(__builtin_amdgcn_exp2f)
    return __builtin_amdgcn_exp2f(x);
#else
    return exp2f(x);
#endif
}
__device__ inline float fast_tanh(float x) {
    x = fminf(fmaxf(x, -15.f), 15.f);
    float t = fexp2(2.885390081777927f * x);   // e^{2x}
    return (t - 1.f) / (t + 1.f);
}
__device__ inline float sigmoidf_(float x) {
    x = fminf(fmaxf(x, -30.f), 30.f);
    float t = fexp2(-1.4426950408889634f * x); // e^{-x}
    return 1.f / (1.f + t);
}

// 16x16 output tile, K-loop, A[m][k] rows (lane&15 -> m, lane>>4 -> k-octet),
// B given as W[n][k] row-major (so B[k][n] frag = contiguous k in row n).
__device__ inline f32x4 mfma_loop(const u16* __restrict__ a, const u16* __restrict__ b, int K) {
    f32x4 acc = {0.f, 0.f, 0.f, 0.f};
#pragma unroll 4
    for (int k = 0; k < K; k += 32) {
        short8 av = *(const short8*)(a + k);
        short8 bv = *(const short8*)(b + k);
        acc = __builtin_amdgcn_mfma_f32_16x16x32_bf16(av, bv, acc, 0, 0, 0);
    }
    return acc;
}

__global__ __launch_bounds__(256) void k_f2bf(const float* __restrict__ src,
                                              u16* __restrict__ dst, int n) {
    int i = blockIdx.x * 256 + threadIdx.x;
    if (i < n) dst[i] = f2bf(src[i]);
}

// xg[t][b][n] = input[b,t,:] @ W_in.T + b_in   (M = T*B, m = t*64+b)
__global__ __launch_bounds__(256) void k_xg_gemm(const u16* __restrict__ inbf,
                                                 const u16* __restrict__ winbf,
                                                 const float* __restrict__ b_in,
                                                 u16* __restrict__ xg) {
    int lane = threadIdx.x & 63, wave = threadIdx.x >> 6;
    int tile = blockIdx.x * 4 + wave;     // 262144 tiles
    int mt = tile >> 8, nt = tile & 255;  // tiles_n = 4096/16 = 256
    int kq = (lane >> 4) * 8;
    int arow = mt * 16 + (lane & 15);
    int t = arow >> 6, b = arow & 63;
    const u16* ap = inbf + ((size_t)(b * TT + t)) * II + kq;
    const u16* bp = winbf + ((size_t)(nt * 16 + (lane & 15))) * II + kq;
    f32x4 acc = mfma_loop(ap, bp, II);
    int n = nt * 16 + (lane & 15);
    float bias = b_in[n];
    int mbase = mt * 16 + (lane >> 4) * 4;
#pragma unroll
    for (int r = 0; r < 4; ++r) {
        int m = mbase + r;
        xg[(size_t)m * H4 + n] = f2bf(acc[r] + bias);
    }
}

// source[b,s,:] = ctx[b,s,:] @ Wa_c.T + ba_c   (M = B*S natural order), bf16 out
__global__ __launch_bounds__(256) void k_src_gemm(const u16* __restrict__ ctxbf,
                                                  const u16* __restrict__ wacbf,
                                                  const float* __restrict__ ba_c,
                                                  u16* __restrict__ srcbf) {
    int lane = threadIdx.x & 63, wave = threadIdx.x >> 6;
    int tile = blockIdx.x * 4 + wave;    // 65536 tiles
    int mt = tile >> 6, nt = tile & 63;  // tiles_n = 64
    int kq = (lane >> 4) * 8;
    const u16* ap = ctxbf + ((size_t)(mt * 16 + (lane & 15))) * HH + kq;
    const u16* bp = wacbf + ((size_t)(nt * 16 + (lane & 15))) * HH + kq;
    f32x4 acc = mfma_loop(ap, bp, HH);
    int n = nt * 16 + (lane & 15);
    float bias = ba_c[n];
    int mbase = mt * 16 + (lane >> 4) * 4;
#pragma unroll
    for (int r = 0; r < 4; ++r) {
        int m = mbase + r;
        srcbf[(size_t)m * HH + n] = f2bf(acc[r] + bias);
    }
}

__global__ __launch_bounds__(256) void k_init(const float* __restrict__ hx0,
                                              const float* __restrict__ cx0,
                                              float* __restrict__ cell,
                                              u16* __restrict__ abuf2) {
    int i = blockIdx.x * 256 + threadIdx.x;  // 65536 = B*H
    cell[i] = cx0[i];
    int b = i >> 10, h = i & 1023;
    abuf2[b * H2 + HH + h] = f2bf(hx0[i]);
}

// gates[b,n] = hy@W_hid.T + b_hid + xg[t,b,n]   (M=64, N=4096, K=1024)
__global__ __launch_bounds__(256) void k_gates_gemm(const u16* __restrict__ hybf,
                                                    const u16* __restrict__ whidbf,
                                                    const u16* __restrict__ xg_t,
                                                    const float* __restrict__ b_hid,
                                                    float* __restrict__ gates) {
    int lane = threadIdx.x & 63, wave = threadIdx.x >> 6;
    int tile = blockIdx.x * 4 + wave;     // 1024 tiles
    int mt = tile >> 8, nt = tile & 255;
    int kq = (lane >> 4) * 8;
    const u16* ap = hybf + (size_t)(mt * 16 + (lane & 15)) * H2 + kq;   // stride 2H
    const u16* bp = whidbf + (size_t)(nt * 16 + (lane & 15)) * HH + kq;
    f32x4 acc = mfma_loop(ap, bp, HH);
    int n = nt * 16 + (lane & 15);
    float bias = b_hid[n];
    int mbase = mt * 16 + (lane >> 4) * 4;
#pragma unroll
    for (int r = 0; r < 4; ++r) {
        int m = mbase + r;
        gates[(size_t)m * H4 + n] = acc[r] + bias + bf2f(xg_t[(size_t)m * H4 + n]);
    }
}

__global__ __launch_bounds__(256) void k_lstm(const float* __restrict__ gates,
                                              float* __restrict__ cell,
                                              float* __restrict__ outh_t,
                                              u16* __restrict__ abuf2) {
    int i = blockIdx.x * 256 + threadIdx.x;  // 65536
    int b = i >> 10, h = i & 1023;
    const float* g = gates + (size_t)b * H4;
    float ig = sigmoidf_(g[h]);
    float fg = sigmoidf_(g[HH + h]);
    float gg = fast_tanh(g[2 * HH + h]);
    float og = sigmoidf_(g[3 * HH + h]);
    float cy = fg * cell[i] + ig * gg;
    float hy = og * fast_tanh(cy);
    cell[i] = cy;
    outh_t[(size_t)b * TT * HH + h] = hy;       // h_out[b,t,:]
    abuf2[b * H2 + HH + h] = f2bf(hy);
}

// target[b,n] = hy @ Wa_in.T   (M=64, N=1024, K=1024)
__global__ __launch_bounds__(256) void k_target_gemm(const u16* __restrict__ hybf,
                                                     const u16* __restrict__ wainbf,
                                                     float* __restrict__ target) {
    int lane = threadIdx.x & 63, wave = threadIdx.x >> 6;
    int tile = blockIdx.x * 4 + wave;    // 256 tiles
    int mt = tile >> 6, nt = tile & 63;
    int kq = (lane >> 4) * 8;
    const u16* ap = hybf + (size_t)(mt * 16 + (lane & 15)) * H2 + kq;
    const u16* bp = wainbf + (size_t)(nt * 16 + (lane & 15)) * HH + kq;
    f32x4 acc = mfma_loop(ap, bp, HH);
    int n = nt * 16 + (lane & 15);
    int mbase = mt * 16 + (lane >> 4) * 4;
#pragma unroll
    for (int r = 0; r < 4; ++r) {
        int m = mbase + r;
        target[(size_t)m * HH + n] = acc[r];
    }
}

// e[b,s] = sum_h tanh(target[b,h] + source[b,s,h]) * Wa_v[h]
__global__ __launch_bounds__(256) void k_energy(const float* __restrict__ target,
                                                const u16* __restrict__ srcbf,
                                                const float* __restrict__ wav,
                                                float* __restrict__ ebuf) {
    int b = blockIdx.x >> 4;
    int chunk = blockIdx.x & 15;
    int lane = threadIdx.x & 63, wave = threadIdx.x >> 6;
    const float* tg = target + (size_t)b * HH;
    float tgv[16], wv[16];
#pragma unroll
    for (int j = 0; j < 16; ++j) {
        int h = lane + 64 * j;
        tgv[j] = tg[h];
        wv[j] = wav[h];
    }
#pragma unroll
    for (int r = 0; r < 4; ++r) {
        int s = chunk * 16 + wave * 4 + r;
        const u16* sp = srcbf + (size_t)(b * SS + s) * HH + lane;
        float acc = 0.f;
#pragma unroll
        for (int j = 0; j < 16; ++j)
            acc += fast_tanh(tgv[j] + bf2f(sp[64 * j])) * wv[j];
        for (int m = 32; m >= 1; m >>= 1) acc += __shfl_xor(acc, m);
        if (lane == 0) ebuf[b * SS + s] = acc;
    }
}

__global__ __launch_bounds__(256) void k_softmax(const float* __restrict__ ebuf,
                                                 float* __restrict__ attn,
                                                 float* __restrict__ out_attn_t) {
    int b = blockIdx.x, s = threadIdx.x;
    __shared__ float red[256];
    float x = ebuf[b * SS + s];
    red[s] = x;
    __syncthreads();
    for (int st = 128; st >= 1; st >>= 1) {
        if (s < st) red[s] = fmaxf(red[s], red[s + st]);
        __syncthreads();
    }
    float mx = red[0];
    __syncthreads();
    float p = fexp2((x - mx) * 1.4426950408889634f);
    red[s] = p;
    __syncthreads();
    for (int st = 128; st >= 1; st >>= 1) {
        if (s < st) red[s] += red[s + st];
        __syncthreads();
    }
    float a = p / red[0];
    attn[b * SS + s] = a;
    out_attn_t[(size_t)b * TT * SS + s] = a;    // attn_out[b,t,:]
}

// c[b,h] = sum_s attn[b,s] * ctx[b,s,h]
__global__ __launch_bounds__(256) void k_context(const float* __restrict__ attn,
                                                 const u16* __restrict__ ctxbf,
                                                 float* __restrict__ outc_t,
                                                 u16* __restrict__ abuf2) {
    int b = blockIdx.x >> 2, ch = blockIdx.x & 3;
    int h = ch * 256 + threadIdx.x;
    __shared__ float a_s[SS];
    a_s[threadIdx.x] = attn[b * SS + threadIdx.x];
    __syncthreads();
    const u16* cp = ctxbf + (size_t)b * SS * HH + h;
    float acc = 0.f;
#pragma unroll 4
    for (int s = 0; s < SS; ++s) acc += a_s[s] * bf2f(cp[(size_t)s * HH]);
    outc_t[(size_t)b * TT * HH + h] = acc;      // c_out[b,t,:]
    abuf2[b * H2 + h] = f2bf(acc);
}

// h_tilde[b,n] = tanh([c,hy] @ Wa_out.T)   (M=64, N=1024, K=2048)
__global__ __launch_bounds__(256) void k_htilde_gemm(const u16* __restrict__ abuf2,
                                                     const u16* __restrict__ waoutbf,
                                                     float* __restrict__ outht_t) {
    int lane = threadIdx.x & 63, wave = threadIdx.x >> 6;
    int tile = blockIdx.x * 4 + wave;    // 256 tiles
    int mt = tile >> 6, nt = tile & 63;
    int kq = (lane >> 4) * 8;
    const u16* ap = abuf2 + (size_t)(mt * 16 + (lane & 15)) * H2 + kq;
    const u16* bp = waoutbf + (size_t)(nt * 16 + (lane & 15)) * H2 + kq;
    f32x4 acc = mfma_loop(ap, bp, H2);
    int n = nt * 16 + (lane & 15);
    int mbase = mt * 16 + (lane >> 4) * 4;
#pragma unroll
    for (int r = 0; r < 4; ++r) {
        int m = mbase + r;
        outht_t[(size_t)m * TT * HH + n] = fast_tanh(acc[r]);
    }
}

__global__ __launch_bounds__(256) void k_final(const float* __restrict__ cell,
                                               float* __restrict__ out) {
    int i = blockIdx.x * 256 + threadIdx.x;  // 65536
    int b = i >> 10, h = i & 1023;
    size_t hy_off = 3 * BTH + BTS;
    out[hy_off + i] = out[(size_t)b * TT * HH + (size_t)(TT - 1) * HH + h];
    out[hy_off + (size_t)BB * HH + i] = cell[i];
}

extern "C" void kernel_launch(void* const* d_in, const int* in_sizes, int n_in,
                              void* d_out, int out_size, void* d_ws, size_t ws_size,
                              hipStream_t stream) {
    const float* input  = (const float*)d_in[0];
    const float* hx0    = (const float*)d_in[1];
    const float* cx0    = (const float*)d_in[2];
    const float* ctx    = (const float*)d_in[3];
    const float* W_in   = (const float*)d_in[4];
    const float* b_in   = (const float*)d_in[5];
    const float* W_hid  = (const float*)d_in[6];
    const float* b_hid  = (const float*)d_in[7];
    const float* Wa_in  = (const float*)d_in[8];
    const float* Wa_c   = (const float*)d_in[9];
    const float* ba_c   = (const float*)d_in[10];
    const float* Wa_v   = (const float*)d_in[11];
    const float* Wa_out = (const float*)d_in[12];
    float* out = (float*)d_out;
    (void)in_sizes; (void)n_in; (void)out_size; (void)ws_size;

    char* w = (char*)d_ws;
    size_t off = 0;
    auto take = [&](size_t bytes) -> void* {
        void* p = w + off;
        off += (bytes + 255) & ~(size_t)255;
        return p;
    };
    u16* xg      = (u16*)take((size_t)TT * BB * H4 * 2);   // 128 MB
    u16* srcbf   = (u16*)take((size_t)BB * SS * HH * 2);   // 32 MB
    u16* ctxbf   = (u16*)take((size_t)BB * SS * HH * 2);   // 32 MB
    u16* inbf    = (u16*)take((size_t)BB * TT * II * 2);   // 32 MB
    u16* winbf   = (u16*)take((size_t)H4 * II * 2);        // 8 MB
    u16* whidbf  = (u16*)take((size_t)H4 * HH * 2);        // 8 MB
    u16* wainbf  = (u16*)take((size_t)HH * HH * 2);        // 2 MB
    u16* wacbf   = (u16*)take((size_t)HH * HH * 2);        // 2 MB
    u16* waoutbf = (u16*)take((size_t)HH * H2 * 2);        // 4 MB
    float* gates  = (float*)take((size_t)BB * H4 * 4);
    float* target = (float*)take((size_t)BB * HH * 4);
    float* ebuf   = (float*)take((size_t)BB * SS * 4);
    float* attn   = (float*)take((size_t)BB * SS * 4);
    float* cell   = (float*)take((size_t)BB * HH * 4);
    u16* abuf2    = (u16*)take((size_t)BB * H2 * 2);       // [c | hy] bf16, lda=2H

    // one-time precompute
    k_f2bf<<<(BB * TT * II) / 256, 256, 0, stream>>>(input, inbf, BB * TT * II);
    k_f2bf<<<(H4 * II) / 256, 256, 0, stream>>>(W_in, winbf, H4 * II);
    k_f2bf<<<(H4 * HH) / 256, 256, 0, stream>>>(W_hid, whidbf, H4 * HH);
    k_f2bf<<<(HH * HH) / 256, 256, 0, stream>>>(Wa_in, wainbf, HH * HH);
    k_f2bf<<<(HH * HH) / 256, 256, 0, stream>>>(Wa_c, wacbf, HH * HH);
    k_f2bf<<<(HH * H2) / 256, 256, 0, stream>>>(Wa_out, waoutbf, HH * H2);
    k_f2bf<<<(BB * SS * HH) / 256, 256, 0, stream>>>(ctx, ctxbf, BB * SS * HH);

    k_src_gemm<<<16384, 256, 0, stream>>>(ctxbf, wacbf, ba_c, srcbf);
    k_xg_gemm<<<65536, 256, 0, stream>>>(inbf, winbf, b_in, xg);
    k_init<<<256, 256, 0, stream>>>(hx0, cx0, cell, abuf2);

    const u16* hybf = abuf2 + HH;
    for (int t = 0; t < TT; ++t) {
        k_gates_gemm<<<256, 256, 0, stream>>>(hybf, whidbf, xg + (size_t)t * BB * H4,
                                              b_hid, gates);
        k_lstm<<<256, 256, 0, stream>>>(gates, cell, out + (size_t)t * HH, abuf2);
        k_target_gemm<<<64, 256, 0, stream>>>(hybf, wainbf, target);
        k_energy<<<1024, 256, 0, stream>>>(target, srcbf, Wa_v, ebuf);
        k_softmax<<<64, 256, 0, stream>>>(ebuf, attn, out + 3 * BTH + (size_t)t * SS);
        k_context<<<256, 256, 0, stream>>>(attn, ctxbf, out + 2 * BTH + (size_t)t * HH,
                                           abuf2);
        k_htilde_gemm<<<64, 256, 0, stream>>>(abuf2, waoutbf, out + BTH + (size_t)t * HH);
    }
    k_final<<<256, 256, 0, stream>>>(cell, out);
}